// Round 13
// baseline (245.539 us; speedup 1.0000x reference)
//
#include <hip/hip_runtime.h>
#include <math.h>

// DistanceAggregation v16 — v15 + waterfall-free chase (readfirstlane).
// R12 post-mortem: v15's meanscan hit 126us with VALUBusy 43% — counter
// arithmetic shows ~50 inst per chase step (6x expected) = compiler
// WATERFALL around readlane: lim=r0+4 depends on threadIdx>>6, divergence
// analysis can't prove s uniform anymore (v13/v14 had blockIdx-only limits
// -> scalar readlane, VALUBusy 5.5%). v16 keeps the v15 structure (4 waves/
// block, 32 waves/CU, barrier-free, register lens) and forces s to SGPR via
// __builtin_amdgcn_readfirstlane each step (s IS uniform: built only from
// broadcast readlane results). Everything else identical to v15 (absmax
// preserved). Decision rule: meanscan >= 46.7us => revert to v13 next round.

typedef float v4 __attribute__((ext_vector_type(4)));

#define T_F    1000
#define D_DIM  512
#define NV4    128
#define BAND_W 4
#define RUNB   16           // rows per wave in band kernel
#define RPBB   63           // ceil(999/16)

__device__ __forceinline__ float wave_sum64(float x) {
  x += __shfl_xor(x, 1);
  x += __shfl_xor(x, 2);
  x += __shfl_xor(x, 4);
  x += __shfl_xor(x, 8);
  x += __shfl_xor(x, 16);
  x += __shfl_xor(x, 32);
  return x;
}

__device__ __forceinline__ v4 sel4(bool c, v4 a, v4 b) {
  v4 r;
  r.x = c ? a.x : b.x; r.y = c ? a.y : b.y;
  r.z = c ? a.z : b.z; r.w = c ? a.w : b.w;
  return r;
}

// ---------------------------------------------------------------- kernel 1
__global__ __launch_bounds__(256)
void band_kernel(const float* __restrict__ data, const float* __restrict__ thrp,
                 unsigned char* __restrict__ deltab, int B) {
  const int lane = threadIdx.x & 63;
  const int wid  = threadIdx.x >> 6;
  const int run  = blockIdx.x * 4 + wid;
  if (run >= B * RPBB) return;
  const int b   = run / RPBB;
  const int s0i = (run % RPBB) * RUNB;       // s0i % 16 == 0

  const v4* __restrict__ dp = reinterpret_cast<const v4*>(data) + (size_t)b * T_F * NV4;
  unsigned char* __restrict__ dbp = deltab + (size_t)b * 1024;

  // per-lane threshold^2 for w = lane&3:  F[w] = 1.9/(1+exp(w-1))+0.4
  const int   wl  = lane & 3;
  const float thr = thrp[0];
  float Ff  = 1.9f / (1.0f + expf((float)wl - 1.0f)) + 0.4f;
  float tt  = thr * Ff;
  const float tf2l = tt * tt;

  const int q0 = lane, q1 = 64 + lane;
  // ring: slot t&7 holds frame t; init frames s0i..s0i+7 (clamped)
  v4 ra[8], rb[8];
#pragma unroll
  for (int d = 0; d < 8; ++d) {
    int t = s0i + d; if (t > T_F - 1) t = T_F - 1;
    ra[d] = dp[(size_t)t * NV4 + q0];
    rb[d] = dp[(size_t)t * NV4 + q1];
  }

  v4 pna[3], pnb[3];                         // 3-deep pending prefetch
  unsigned long long packed = 0ull;          // 16 delta nibbles

#pragma unroll
  for (int u = 0; u < RUNB; ++u) {
    const int s  = s0i + u;                  // segment start; slot = u&7
    const int su = u & 7;
    float p[BAND_W];
#pragma unroll
    for (int w = 0; w < BAND_W; ++w) {
      const int sj = (u + 1 + w) & 7;        // slot of frame s+1+w (compile-time)
      v4 d0 = ra[su] - ra[sj];
      v4 d1 = rb[su] - rb[sj];
      p[w] = d0.x*d0.x + d0.y*d0.y + d0.z*d0.z + d0.w*d0.w
           + d1.x*d1.x + d1.y*d1.y + d1.z*d1.z + d1.w*d1.w;
    }
    // commit pending prefetch issued 3 rows ago: frame s+5 lands in slot
    // (u+5)&7 (held frame s-3, dead after row u-3; first read at row u+1)
    if (u >= 3 && (u - 3) < RUNB - 4) {
      const int cs = (u + 5) & 7;
      ra[cs] = pna[u % 3];
      rb[cs] = pnb[u % 3];
    }
    // issue prefetch of frame s+8 (rows >= RUNB-4 would load frames nobody
    // reads -- skip them: 24 -> 20 frames per run)
    if (u < RUNB - 4) {
      int tn = s + 8; if (tn > T_F - 1) tn = T_F - 1;
      pna[u % 3] = dp[(size_t)tn * NV4 + q0];
      pnb[u % 3] = dp[(size_t)tn * NV4 + q1];
    }

#pragma unroll
    for (int w = 0; w < BAND_W; ++w) {
      p[w] += __shfl_xor(p[w], 1);
      p[w] += __shfl_xor(p[w], 2);
      p[w] += __shfl_xor(p[w], 4);
    }
    const bool bt0 = (lane & 1) != 0, bt1 = (lane & 2) != 0;
    float q0v  = bt0 ? p[1] : p[0];
    float q1v  = bt0 ? p[3] : p[2];
    float comb = bt1 ? q1v : q0v;
    comb += __shfl_xor(comb, 8);
    comb += __shfl_xor(comb, 16);
    comb += __shfl_xor(comb, 32);
    // lane L now holds full dist^2 for w = L&3
    bool valid = (s + 1 + wl) <= (T_F - 1);
    bool bnd   = valid && (comb > tf2l);
    unsigned long long m = __ballot(bnd);
    unsigned long long delta =
        (unsigned long long)__ffsll((unsigned long long)(m & 0xFull)); // 1..4, 0 = none
    packed |= delta << (4 * u);
  }
  // one aligned 8B store of 16 nibbles per run (rows s0i..s0i+15)
  if (lane == 0)
    *reinterpret_cast<unsigned long long*>(dbp + (s0i >> 1)) = packed;
}

// ---------------------------------------------------------------- kernel 2
// 4 waves/block, no barrier: each wave redundantly chases (wave-uniform) up
// to its own 4-row sub-window, lens in a register. s forced to SGPR each
// step via readfirstlane -> no waterfall around readlane.
__global__ __launch_bounds__(256)
void meanscan_kernel(const float* __restrict__ data,
                     const float* __restrict__ thrp,
                     const unsigned char* __restrict__ deltab,
                     float* __restrict__ out, int B) {
  const int lane = threadIdx.x & 63;
  const int wv   = threadIdx.x >> 6;             // 0..3
  const int b    = blockIdx.y;
  const int X    = blockIdx.x * 16;              // window rows X..X+15
  const int r0   = X + wv * 4;                   // this wave: rows r0..r0+3

  const v4* __restrict__ dp  = reinterpret_cast<const v4*>(data) + (size_t)b * T_F * NV4;
  v4* __restrict__ mp        = reinterpret_cast<v4*>(out) + (size_t)b * (T_F - 1) * NV4;
  float* __restrict__ fl     = out + (size_t)B * (T_F - 1) * D_DIM + (size_t)b * (T_F - 1);
  const int q0 = lane, q1 = 64 + lane;

  // lane L holds rows 16L..16L+15 packed nibbles (lo = rows 0..7, hi = 8..15)
  const uint2 dd = reinterpret_cast<const uint2*>(deltab + (size_t)b * 1024)[lane];
  const unsigned plo = dd.x;
  const unsigned phi = dd.y;

  unsigned lenp = 0;                             // len nibble per own row
  int s = 0;
  bool need_exact = false;
  const int lim = r0 + 4;
  while (s < T_F - 1 && s < lim) {
    // s is uniform (built only from broadcast readlane results); pin it to
    // an SGPR so the compiler emits scalar readlane, not a waterfall.
    const int su = __builtin_amdgcn_readfirstlane(s);
    unsigned lo = (unsigned)__builtin_amdgcn_readlane((int)plo, su >> 4);
    unsigned hi = (unsigned)__builtin_amdgcn_readlane((int)phi, su >> 4);
    unsigned word = (su & 8) ? hi : lo;
    int delta = (word >> ((su & 7) * 4)) & 15;
    if (delta == 0) { need_exact = (su < T_F - 1 - BAND_W); break; }
    int ns = su + delta;
    if (ns >= r0 && ns < lim)
      lenp |= (unsigned)delta << (4 * (ns - r0));
    s = ns;
  }

  // so per own row (register-resident; cold path overwrites via cmp-select)
  int soA = (lenp & 15u)        ? (r0 + 0 - (int)( lenp        & 15u)) : -1;
  int soB = ((lenp >> 4) & 15u) ? (r0 + 1 - (int)((lenp >> 4)  & 15u)) : -1;
  int soC = ((lenp >> 8) & 15u) ? (r0 + 2 - (int)((lenp >> 8)  & 15u)) : -1;
  int soD = ((lenp >> 12) & 15u)? (r0 + 3 - (int)((lenp >> 12) & 15u)) : -1;

  if (need_exact) {   // cold (never hit on this data): exact continuation
    const float thr = thrp[0];
    int ind = __builtin_amdgcn_readfirstlane(s), f = 0;
    v4 rep0 = dp[(size_t)ind * NV4 + q0];
    v4 rep1 = dp[(size_t)ind * NV4 + q1];
    int iend = r0 + 3; if (iend > T_F - 1) iend = T_F - 1;
    for (int i = ind + 1; i <= iend; ++i) {
      float av = fminf((float)f - 1.0f, 80.0f);
      float Ff = 1.9f / (1.0f + expf(av)) + 0.4f;
      float t2 = thr * Ff; t2 *= t2;
      v4 x0 = dp[(size_t)i * NV4 + q0];
      v4 x1 = dp[(size_t)i * NV4 + q1];
      v4 d0 = rep0 - x0, d1 = rep1 - x1;
      float part = d0.x*d0.x + d0.y*d0.y + d0.z*d0.z + d0.w*d0.w
                 + d1.x*d1.x + d1.y*d1.y + d1.z*d1.z + d1.w*d1.w;
      float d2 = wave_sum64(part);
      bool bnd = d2 > t2;
      if (bnd) {
        soA = (i == r0 + 0) ? ind : soA;
        soB = (i == r0 + 1) ? ind : soB;
        soC = (i == r0 + 2) ? ind : soC;
        soD = (i == r0 + 3) ? ind : soD;
        ind = i; f = 0; rep0 = x0; rep1 = x1;
      } else {
        f += 1;
      }
    }
  }

  const int soarr[4] = {soA, soB, soC, soD};
  const v4 z = {0.f, 0.f, 0.f, 0.f};
#pragma unroll
  for (int e = 0; e < 4; ++e) {
    const int i = r0 + e;
    if (i < 1 || i > T_F - 1) continue;
    const int sv = soarr[e];                    // static index (unrolled)
    if (sv < 0) {
      __builtin_nontemporal_store(z, &mp[(size_t)(i - 1) * NV4 + q0]);
      __builtin_nontemporal_store(z, &mp[(size_t)(i - 1) * NV4 + q1]);
      if (lane == 0) __builtin_nontemporal_store(0.0f, &fl[i - 1]);
      continue;
    }
    const int len = i - sv;                     // wave-uniform
    v4 a0 = z, a1 = z;
    if (len <= BAND_W) {                        // hot: branch-free masked gather
#pragma unroll
      for (int j = 0; j < BAND_W; ++j) {
        const int t = (j < len) ? (sv + j) : (i - 1);  // clamped, in-segment
        const float msk = (j < len) ? 1.0f : 0.0f;
        v4 x0 = dp[(size_t)t * NV4 + q0];
        v4 x1 = dp[(size_t)t * NV4 + q1];
        a0.x += x0.x * msk; a0.y += x0.y * msk; a0.z += x0.z * msk; a0.w += x0.w * msk;
        a1.x += x1.x * msk; a1.y += x1.y * msk; a1.z += x1.z * msk; a1.w += x1.w * msk;
      }
    } else {                                    // cold: post-fallback long segment
      for (int t = sv; t < i; ++t) {
        a0 += dp[(size_t)t * NV4 + q0];
        a1 += dp[(size_t)t * NV4 + q1];
      }
    }
    const float inv = 1.0f / (float)len;
    a0.x *= inv; a0.y *= inv; a0.z *= inv; a0.w *= inv;
    a1.x *= inv; a1.y *= inv; a1.z *= inv; a1.w *= inv;
    __builtin_nontemporal_store(a0, &mp[(size_t)(i - 1) * NV4 + q0]);
    __builtin_nontemporal_store(a1, &mp[(size_t)(i - 1) * NV4 + q1]);
    if (lane == 0) __builtin_nontemporal_store(1.0f, &fl[i - 1]);
  }
}

// --------------------------------------------------- fallback (R2, green)
__global__ __launch_bounds__(64, 1)
void dist_agg_mono(const float* __restrict__ data,
                   const float* __restrict__ thrp,
                   float* __restrict__ out, int B) {
  const int b    = blockIdx.x;
  const int lane = threadIdx.x;
  const float thr = thrp[0];
  const v4* __restrict__ dp = reinterpret_cast<const v4*>(data) + (size_t)b * T_F * NV4;
  v4* __restrict__ mp       = reinterpret_cast<v4*>(out) + (size_t)b * (T_F - 1) * NV4;
  float* __restrict__ fp    = out + (size_t)B * (T_F - 1) * D_DIM + (size_t)b * (T_F - 1);
  const int s0 = lane, s1 = 64 + lane;

  v4 rep0 = dp[s0], rep1 = dp[s1];
  v4 cs0  = rep0,  cs1  = rep1;
  v4 ss0  = {0.f,0.f,0.f,0.f}, ss1 = {0.f,0.f,0.f,0.f};
  int ind = 0, fi = 0;
  const float F0     = 1.9f / (1.0f + expf(-1.0f)) + 0.4f;
  const float tf0    = thr * F0;
  const float tf2_f0 = tf0 * tf0;
  float tf2 = tf2_f0;

  for (int i = 1; i < T_F; ++i) {
    float an      = fminf((float)fi, 80.0f);
    float Fn      = 1.9f / (1.0f + expf(an)) + 0.4f;
    float tn      = thr * Fn;
    float tf2_inc = tn * tn;
    v4 fa = dp[(size_t)i * NV4 + s0];
    v4 fb = dp[(size_t)i * NV4 + s1];
    v4 d0 = rep0 - fa, d1 = rep1 - fb;
    float part = d0.x*d0.x + d0.y*d0.y + d0.z*d0.z + d0.w*d0.w
               + d1.x*d1.x + d1.y*d1.y + d1.z*d1.z + d1.w*d1.w;
    float dist2 = wave_sum64(part);
    bool bnd = dist2 > tf2;
    float inv = 1.0f / (float)(i - ind);
    v4 df0 = cs0 - ss0, df1 = cs1 - ss1;
    v4 m0, m1, z = {0.f,0.f,0.f,0.f};
    m0.x = df0.x*inv; m0.y = df0.y*inv; m0.z = df0.z*inv; m0.w = df0.w*inv;
    m1.x = df1.x*inv; m1.y = df1.y*inv; m1.z = df1.z*inv; m1.w = df1.w*inv;
    mp[(size_t)(i-1) * NV4 + s0] = sel4(bnd, m0, z);
    mp[(size_t)(i-1) * NV4 + s1] = sel4(bnd, m1, z);
    if (lane == 0) fp[i-1] = bnd ? 1.0f : 0.0f;
    rep0 = sel4(bnd, fa, rep0); rep1 = sel4(bnd, fb, rep1);
    ss0  = sel4(bnd, cs0, ss0); ss1  = sel4(bnd, cs1, ss1);
    ind  = bnd ? i : ind;
    fi   = bnd ? 0 : fi + 1;
    tf2  = bnd ? tf2_f0 : tf2_inc;
    cs0 += fa; cs1 += fb;
  }
}

// ----------------------------------------------------------------- launch
extern "C" void kernel_launch(void* const* d_in, const int* in_sizes, int n_in,
                              void* d_out, int out_size, void* d_ws, size_t ws_size,
                              hipStream_t stream) {
  const float* data = (const float*)d_in[0];
  const float* thr  = (const float*)d_in[1];
  float* out        = (float*)d_out;
  const int B = in_sizes[0] / (T_F * D_DIM);

  const size_t need = (size_t)B * 1024;   // deltab only

  if (ws_size >= need) {
    unsigned char* deltab = (unsigned char*)d_ws;
    const int runs = B * RPBB;
    band_kernel<<<(runs + 3) / 4, 256, 0, stream>>>(data, thr, deltab, B);
    meanscan_kernel<<<dim3(63, B), 256, 0, stream>>>(data, thr, deltab, out, B);
  } else {
    dist_agg_mono<<<B, 64, 0, stream>>>(data, thr, out, B);
  }
}

// Round 14
// 147.146 us; speedup vs baseline: 1.6687x; 1.6687x over previous
//
#include <hip/hip_runtime.h>
#include <math.h>

// DistanceAggregation v13 (verbatim revert — R9's measured 147.4us, session
// best). R10-R12 post-mortems: three attempts to beat v13's 46.7us meanscan
// failed (v14 1-wave: 52us, occupancy 7.9 waves/CU; v15 4-wave redundant
// chase: 126us, waterfall from threadIdx-dependent loop limit; v16 +
// readfirstlane: 149us — divergent CONTROL FLOW keeps the loop exec-masked,
// readfirstlane adds VALU->SALU round-trips, VALU-cycles 36us-equiv vs v13's
// 4.7). Decision rule fired: revert. v13 structure: band (nibble-packed
// delta u64/run) + meanscan (4 waves, wave0 chases with blockIdx-only limit
// -> scalar loop, LDS so[16], one barrier, branch-free masked-4 gathers).

typedef float v4 __attribute__((ext_vector_type(4)));

#define T_F    1000
#define D_DIM  512
#define NV4    128
#define BAND_W 4
#define RUNB   16           // rows per wave in band kernel
#define RPBB   63           // ceil(999/16)

__device__ __forceinline__ float wave_sum64(float x) {
  x += __shfl_xor(x, 1);
  x += __shfl_xor(x, 2);
  x += __shfl_xor(x, 4);
  x += __shfl_xor(x, 8);
  x += __shfl_xor(x, 16);
  x += __shfl_xor(x, 32);
  return x;
}

__device__ __forceinline__ v4 sel4(bool c, v4 a, v4 b) {
  v4 r;
  r.x = c ? a.x : b.x; r.y = c ? a.y : b.y;
  r.z = c ? a.z : b.z; r.w = c ? a.w : b.w;
  return r;
}

// ---------------------------------------------------------------- kernel 1
__global__ __launch_bounds__(256)
void band_kernel(const float* __restrict__ data, const float* __restrict__ thrp,
                 unsigned char* __restrict__ deltab, int B) {
  const int lane = threadIdx.x & 63;
  const int wid  = threadIdx.x >> 6;
  const int run  = blockIdx.x * 4 + wid;
  if (run >= B * RPBB) return;
  const int b   = run / RPBB;
  const int s0i = (run % RPBB) * RUNB;       // s0i % 16 == 0

  const v4* __restrict__ dp = reinterpret_cast<const v4*>(data) + (size_t)b * T_F * NV4;
  unsigned char* __restrict__ dbp = deltab + (size_t)b * 1024;

  // per-lane threshold^2 for w = lane&3:  F[w] = 1.9/(1+exp(w-1))+0.4
  const int   wl  = lane & 3;
  const float thr = thrp[0];
  float Ff  = 1.9f / (1.0f + expf((float)wl - 1.0f)) + 0.4f;
  float tt  = thr * Ff;
  const float tf2l = tt * tt;

  const int q0 = lane, q1 = 64 + lane;
  // ring: slot t&7 holds frame t; init frames s0i..s0i+7 (clamped)
  v4 ra[8], rb[8];
#pragma unroll
  for (int d = 0; d < 8; ++d) {
    int t = s0i + d; if (t > T_F - 1) t = T_F - 1;
    ra[d] = dp[(size_t)t * NV4 + q0];
    rb[d] = dp[(size_t)t * NV4 + q1];
  }

  v4 pna[3], pnb[3];                         // 3-deep pending prefetch
  unsigned long long packed = 0ull;          // 16 delta nibbles

#pragma unroll
  for (int u = 0; u < RUNB; ++u) {
    const int s  = s0i + u;                  // segment start; slot = u&7
    const int su = u & 7;
    float p[BAND_W];
#pragma unroll
    for (int w = 0; w < BAND_W; ++w) {
      const int sj = (u + 1 + w) & 7;        // slot of frame s+1+w (compile-time)
      v4 d0 = ra[su] - ra[sj];
      v4 d1 = rb[su] - rb[sj];
      p[w] = d0.x*d0.x + d0.y*d0.y + d0.z*d0.z + d0.w*d0.w
           + d1.x*d1.x + d1.y*d1.y + d1.z*d1.z + d1.w*d1.w;
    }
    // commit pending prefetch issued 3 rows ago: frame s+5 lands in slot
    // (u+5)&7 (held frame s-3, dead after row u-3; first read at row u+1)
    if (u >= 3 && (u - 3) < RUNB - 4) {
      const int cs = (u + 5) & 7;
      ra[cs] = pna[u % 3];
      rb[cs] = pnb[u % 3];
    }
    // issue prefetch of frame s+8 (rows >= RUNB-4 would load frames nobody
    // reads -- skip them: 24 -> 20 frames per run)
    if (u < RUNB - 4) {
      int tn = s + 8; if (tn > T_F - 1) tn = T_F - 1;
      pna[u % 3] = dp[(size_t)tn * NV4 + q0];
      pnb[u % 3] = dp[(size_t)tn * NV4 + q1];
    }

#pragma unroll
    for (int w = 0; w < BAND_W; ++w) {
      p[w] += __shfl_xor(p[w], 1);
      p[w] += __shfl_xor(p[w], 2);
      p[w] += __shfl_xor(p[w], 4);
    }
    const bool bt0 = (lane & 1) != 0, bt1 = (lane & 2) != 0;
    float q0v  = bt0 ? p[1] : p[0];
    float q1v  = bt0 ? p[3] : p[2];
    float comb = bt1 ? q1v : q0v;
    comb += __shfl_xor(comb, 8);
    comb += __shfl_xor(comb, 16);
    comb += __shfl_xor(comb, 32);
    // lane L now holds full dist^2 for w = L&3
    bool valid = (s + 1 + wl) <= (T_F - 1);
    bool bnd   = valid && (comb > tf2l);
    unsigned long long m = __ballot(bnd);
    unsigned long long delta =
        (unsigned long long)__ffsll((unsigned long long)(m & 0xFull)); // 1..4, 0 = none
    packed |= delta << (4 * u);
  }
  // one aligned 8B store of 16 nibbles per run (rows s0i..s0i+15)
  if (lane == 0)
    *reinterpret_cast<unsigned long long*>(dbp + (s0i >> 1)) = packed;
}

// ---------------------------------------------------------------- kernel 2
// Per block: wave 0 chases delta[] from 0, early-exit past window [X, X+15],
// records so into LDS; then 4 waves x 4 rows compute means (v12 body).
__global__ __launch_bounds__(256)
void meanscan_kernel(const float* __restrict__ data,
                     const float* __restrict__ thrp,
                     const unsigned char* __restrict__ deltab,
                     float* __restrict__ out, int B) {
  const int lane = threadIdx.x & 63;
  const int wv   = threadIdx.x >> 6;
  const int b    = blockIdx.y;
  const int X    = blockIdx.x * 16;              // window rows X..X+15
  const int i0   = X + wv * 4;                   // this wave: rows i0..i0+3

  const v4* __restrict__ dp  = reinterpret_cast<const v4*>(data) + (size_t)b * T_F * NV4;
  v4* __restrict__ mp        = reinterpret_cast<v4*>(out) + (size_t)b * (T_F - 1) * NV4;
  float* __restrict__ fl     = out + (size_t)B * (T_F - 1) * D_DIM + (size_t)b * (T_F - 1);
  const int q0 = lane, q1 = 64 + lane;

  __shared__ int so_l[16];

  if (wv == 0) {
    if (lane < 16) so_l[lane] = -1;
    // lane L holds rows 16L..16L+15 packed nibbles (lo = rows 0..7, hi = 8..15)
    const uint2 dd = reinterpret_cast<const uint2*>(deltab + (size_t)b * 1024)[lane];
    unsigned plo = dd.x;
    unsigned phi = dd.y;

    int s = 0;
    bool need_exact = false;
    const int lim = X + 16;                      // no landings >= lim matter
    while (s < T_F - 1 && s < lim) {
      unsigned lo = (unsigned)__builtin_amdgcn_readlane((int)plo, s >> 4);
      unsigned hi = (unsigned)__builtin_amdgcn_readlane((int)phi, s >> 4);
      unsigned word = (s & 8) ? hi : lo;
      int delta = (word >> ((s & 7) * 4)) & 15;
      if (delta == 0) { need_exact = (s < T_F - 1 - BAND_W); break; }
      int ns = s + delta;
      if (ns >= X && ns < lim && lane == 0) so_l[ns - X] = s;
      s = ns;
    }

    if (need_exact) {   // cold: exact continuation from last boundary s,
      // only as far as this block's window needs (identical so values to v12)
      const float thr = thrp[0];
      int ind = s, f = 0;
      v4 rep0 = dp[(size_t)ind * NV4 + q0];
      v4 rep1 = dp[(size_t)ind * NV4 + q1];
      int iend = X + 15; if (iend > T_F - 1) iend = T_F - 1;
      for (int i = s + 1; i <= iend; ++i) {
        float av = fminf((float)f - 1.0f, 80.0f);
        float Ff = 1.9f / (1.0f + expf(av)) + 0.4f;
        float t2 = thr * Ff; t2 *= t2;
        v4 x0 = dp[(size_t)i * NV4 + q0];
        v4 x1 = dp[(size_t)i * NV4 + q1];
        v4 d0 = rep0 - x0, d1 = rep1 - x1;
        float part = d0.x*d0.x + d0.y*d0.y + d0.z*d0.z + d0.w*d0.w
                   + d1.x*d1.x + d1.y*d1.y + d1.z*d1.z + d1.w*d1.w;
        float d2 = wave_sum64(part);
        bool bnd = d2 > t2;
        if (bnd) {
          if (i >= X && lane == 0) so_l[i - X] = ind;
          ind = i; f = 0; rep0 = x0; rep1 = x1;
        } else {
          f += 1;
        }
      }
    }
  }
  __syncthreads();

  const v4 z = {0.f, 0.f, 0.f, 0.f};
#pragma unroll
  for (int q = 0; q < 4; ++q) {
    const int i = i0 + q;
    if (i < 1 || i > T_F - 1) continue;
    const int s = so_l[wv * 4 + q];
    if (s < 0) {
      __builtin_nontemporal_store(z, &mp[(size_t)(i - 1) * NV4 + q0]);
      __builtin_nontemporal_store(z, &mp[(size_t)(i - 1) * NV4 + q1]);
      if (lane == 0) __builtin_nontemporal_store(0.0f, &fl[i - 1]);
      continue;
    }
    const int len = i - s;                    // wave-uniform
    v4 a0 = z, a1 = z;
    if (len <= BAND_W) {                      // hot: branch-free masked gather
#pragma unroll
      for (int j = 0; j < BAND_W; ++j) {
        const int t = (j < len) ? (s + j) : (i - 1);   // clamped, in-segment
        const float msk = (j < len) ? 1.0f : 0.0f;
        v4 x0 = dp[(size_t)t * NV4 + q0];
        v4 x1 = dp[(size_t)t * NV4 + q1];
        a0.x += x0.x * msk; a0.y += x0.y * msk; a0.z += x0.z * msk; a0.w += x0.w * msk;
        a1.x += x1.x * msk; a1.y += x1.y * msk; a1.z += x1.z * msk; a1.w += x1.w * msk;
      }
    } else {                                  // cold: post-fallback long segment
      for (int t = s; t < i; ++t) {
        a0 += dp[(size_t)t * NV4 + q0];
        a1 += dp[(size_t)t * NV4 + q1];
      }
    }
    const float inv = 1.0f / (float)len;
    a0.x *= inv; a0.y *= inv; a0.z *= inv; a0.w *= inv;
    a1.x *= inv; a1.y *= inv; a1.z *= inv; a1.w *= inv;
    __builtin_nontemporal_store(a0, &mp[(size_t)(i - 1) * NV4 + q0]);
    __builtin_nontemporal_store(a1, &mp[(size_t)(i - 1) * NV4 + q1]);
    if (lane == 0) __builtin_nontemporal_store(1.0f, &fl[i - 1]);
  }
}

// --------------------------------------------------- fallback (R2, green)
__global__ __launch_bounds__(64, 1)
void dist_agg_mono(const float* __restrict__ data,
                   const float* __restrict__ thrp,
                   float* __restrict__ out, int B) {
  const int b    = blockIdx.x;
  const int lane = threadIdx.x;
  const float thr = thrp[0];
  const v4* __restrict__ dp = reinterpret_cast<const v4*>(data) + (size_t)b * T_F * NV4;
  v4* __restrict__ mp       = reinterpret_cast<v4*>(out) + (size_t)b * (T_F - 1) * NV4;
  float* __restrict__ fp    = out + (size_t)B * (T_F - 1) * D_DIM + (size_t)b * (T_F - 1);
  const int s0 = lane, s1 = 64 + lane;

  v4 rep0 = dp[s0], rep1 = dp[s1];
  v4 cs0  = rep0,  cs1  = rep1;
  v4 ss0  = {0.f,0.f,0.f,0.f}, ss1 = {0.f,0.f,0.f,0.f};
  int ind = 0, fi = 0;
  const float F0     = 1.9f / (1.0f + expf(-1.0f)) + 0.4f;
  const float tf0    = thr * F0;
  const float tf2_f0 = tf0 * tf0;
  float tf2 = tf2_f0;

  for (int i = 1; i < T_F; ++i) {
    float an      = fminf((float)fi, 80.0f);
    float Fn      = 1.9f / (1.0f + expf(an)) + 0.4f;
    float tn      = thr * Fn;
    float tf2_inc = tn * tn;
    v4 fa = dp[(size_t)i * NV4 + s0];
    v4 fb = dp[(size_t)i * NV4 + s1];
    v4 d0 = rep0 - fa, d1 = rep1 - fb;
    float part = d0.x*d0.x + d0.y*d0.y + d0.z*d0.z + d0.w*d0.w
               + d1.x*d1.x + d1.y*d1.y + d1.z*d1.z + d1.w*d1.w;
    float dist2 = wave_sum64(part);
    bool bnd = dist2 > tf2;
    float inv = 1.0f / (float)(i - ind);
    v4 df0 = cs0 - ss0, df1 = cs1 - ss1;
    v4 m0, m1, z = {0.f,0.f,0.f,0.f};
    m0.x = df0.x*inv; m0.y = df0.y*inv; m0.z = df0.z*inv; m0.w = df0.w*inv;
    m1.x = df1.x*inv; m1.y = df1.y*inv; m1.z = df1.z*inv; m1.w = df1.w*inv;
    mp[(size_t)(i-1) * NV4 + s0] = sel4(bnd, m0, z);
    mp[(size_t)(i-1) * NV4 + s1] = sel4(bnd, m1, z);
    if (lane == 0) fp[i-1] = bnd ? 1.0f : 0.0f;
    rep0 = sel4(bnd, fa, rep0); rep1 = sel4(bnd, fb, rep1);
    ss0  = sel4(bnd, cs0, ss0); ss1  = sel4(bnd, cs1, ss1);
    ind  = bnd ? i : ind;
    fi   = bnd ? 0 : fi + 1;
    tf2  = bnd ? tf2_f0 : tf2_inc;
    cs0 += fa; cs1 += fb;
  }
}

// ----------------------------------------------------------------- launch
extern "C" void kernel_launch(void* const* d_in, const int* in_sizes, int n_in,
                              void* d_out, int out_size, void* d_ws, size_t ws_size,
                              hipStream_t stream) {
  const float* data = (const float*)d_in[0];
  const float* thr  = (const float*)d_in[1];
  float* out        = (float*)d_out;
  const int B = in_sizes[0] / (T_F * D_DIM);

  const size_t need = (size_t)B * 1024;   // deltab only (so[] is gone)

  if (ws_size >= need) {
    unsigned char* deltab = (unsigned char*)d_ws;
    const int runs = B * RPBB;
    band_kernel<<<(runs + 3) / 4, 256, 0, stream>>>(data, thr, deltab, B);
    meanscan_kernel<<<dim3(63, B), 256, 0, stream>>>(data, thr, deltab, out, B);
  } else {
    dist_agg_mono<<<B, 64, 0, stream>>>(data, thr, out, B);
  }
}